// Round 1
// baseline (96.709 us; speedup 1.0000x reference)
//
#include <hip/hip_runtime.h>

#define M_ROWS 8192   // B*L
#define DIM    768    // D
#define HCH    128    // H

typedef __bf16 bf16x8 __attribute__((ext_vector_type(8)));
typedef float  f32x4  __attribute__((ext_vector_type(4)));

__device__ __forceinline__ unsigned short f2bf(float f) {
    union { float f; unsigned int u; } v; v.f = f;
    unsigned int u = v.u;
    u += 0x7fffu + ((u >> 16) & 1u);   // round-to-nearest-even
    return (unsigned short)(u >> 16);
}

// W0 f32 [128][768] -> bf16 [128][768] (already the B^T layout MFMA wants)
__global__ __launch_bounds__(256) void convert_w0_kernel(
    const float* __restrict__ W0, unsigned short* __restrict__ W0b)
{
    int i = (blockIdx.x * 256 + threadIdx.x) * 4;   // 98304 / 4 = 24576 threads
    float4 v = *(const float4*)(W0 + i);
    uint2 o;
    o.x = (unsigned int)f2bf(v.x) | ((unsigned int)f2bf(v.y) << 16);
    o.y = (unsigned int)f2bf(v.z) | ((unsigned int)f2bf(v.w) << 16);
    *(uint2*)(W0b + i) = o;
}

// Fused GEMM (M=8192,N=128,K=768, bf16 MFMA) + relu + weighted H-reduction.
// Block: 256 thr = 4 waves in a 2x2 grid over (32 rows x 128 cols). Grid: 256.
__global__ __launch_bounds__(256) void gemm_s_kernel(
    const float* __restrict__ text,
    const unsigned short* __restrict__ W0b,
    const float* __restrict__ b0,
    const float* __restrict__ W1,
    float* __restrict__ s1, float* __restrict__ s2)
{
    // row stride 40 bf16 = 80 B: b128 frag reads/writes land uniformly on banks
    __shared__ unsigned short As[32][40];
    __shared__ unsigned short Bs[128][40];
    __shared__ float red1[32][2];
    __shared__ float red2[32][2];

    const int tid  = threadIdx.x;
    const int lane = tid & 63;
    const int wave = tid >> 6;
    const int row0 = blockIdx.x * 32;

    const int wrow = (wave >> 1) * 16;   // wave row offset (0/16)
    const int wcol = (wave & 1) * 64;    // wave col offset (0/64)
    const int n16  = lane & 15;
    const int quad = lane >> 4;

    // staging maps
    const int am  = tid >> 3;            // A: 32 rows x 32 k, 1 float4/thread
    const int ak4 = (tid & 7) << 2;
    const int bn  = tid >> 2;            // B: 128 rows x 32 k, 2 uint4/thread
    const int bp  = tid & 3;

    const float*          aptr  = text + (size_t)(row0 + am) * DIM + ak4;
    const unsigned short* bptr0 = W0b + (size_t)bn * DIM + bp * 8;
    const unsigned short* bptr1 = bptr0 + (size_t)64 * DIM;

    f32x4 acc[4];
    #pragma unroll
    for (int j = 0; j < 4; ++j) acc[j] = (f32x4){0.f, 0.f, 0.f, 0.f};

    float4 av  = *(const float4*)aptr;
    uint4  bv0 = *(const uint4*)bptr0;
    uint4  bv1 = *(const uint4*)bptr1;

    for (int kt = 0; kt < DIM; kt += 32) {
        const int ktn = (kt + 32 < DIM) ? (kt + 32) : 0;   // harmless reload on last iter
        float4 av_n  = *(const float4*)(aptr + ktn);
        uint4  bv0_n = *(const uint4*)(bptr0 + ktn);
        uint4  bv1_n = *(const uint4*)(bptr1 + ktn);

        // stage current tile into LDS (A: f32 -> bf16 on the fly)
        uint2 o;
        o.x = (unsigned int)f2bf(av.x) | ((unsigned int)f2bf(av.y) << 16);
        o.y = (unsigned int)f2bf(av.z) | ((unsigned int)f2bf(av.w) << 16);
        *(uint2*)&As[am][ak4]         = o;
        *(uint4*)&Bs[bn][bp * 8]      = bv0;
        *(uint4*)&Bs[bn + 64][bp * 8] = bv1;
        __syncthreads();

        bf16x8 a   = *(const bf16x8*)&As[wrow + n16][quad * 8];
        bf16x8 bf0 = *(const bf16x8*)&Bs[wcol +  0 + n16][quad * 8];
        bf16x8 bf1 = *(const bf16x8*)&Bs[wcol + 16 + n16][quad * 8];
        bf16x8 bf2 = *(const bf16x8*)&Bs[wcol + 32 + n16][quad * 8];
        bf16x8 bf3 = *(const bf16x8*)&Bs[wcol + 48 + n16][quad * 8];
        acc[0] = __builtin_amdgcn_mfma_f32_16x16x32_bf16(a, bf0, acc[0], 0, 0, 0);
        acc[1] = __builtin_amdgcn_mfma_f32_16x16x32_bf16(a, bf1, acc[1], 0, 0, 0);
        acc[2] = __builtin_amdgcn_mfma_f32_16x16x32_bf16(a, bf2, acc[2], 0, 0, 0);
        acc[3] = __builtin_amdgcn_mfma_f32_16x16x32_bf16(a, bf3, acc[3], 0, 0, 0);
        __syncthreads();

        av = av_n; bv0 = bv0_n; bv1 = bv1_n;
    }

    // epilogue: relu + b0, weight by w_a / w_b, reduce over the 128 cols.
    // C/D layout (verified): col = lane&15 (+tile), row = quad*4 + reg
    float p1[4] = {0.f, 0.f, 0.f, 0.f};
    float p2[4] = {0.f, 0.f, 0.f, 0.f};
    #pragma unroll
    for (int j = 0; j < 4; ++j) {
        const int col = wcol + j * 16 + n16;
        const float bb = b0[col];
        const float wa = W1[col];
        const float wb = W1[HCH + col];
        #pragma unroll
        for (int r = 0; r < 4; ++r) {
            float h = acc[j][r] + bb;
            h = fmaxf(h, 0.f);
            p1[r] += h * wa;
            p2[r] += h * wb;
        }
    }
    // reduce across the 16 lanes of each quad (masks < 16 stay inside the quad)
    #pragma unroll
    for (int r = 0; r < 4; ++r) {
        #pragma unroll
        for (int m = 8; m >= 1; m >>= 1) {
            p1[r] += __shfl_xor(p1[r], m);
            p2[r] += __shfl_xor(p2[r], m);
        }
    }
    if (n16 == 0) {
        #pragma unroll
        for (int r = 0; r < 4; ++r) {
            const int rr = wrow + quad * 4 + r;
            red1[rr][wave & 1] = p1[r];
            red2[rr][wave & 1] = p2[r];
        }
    }
    __syncthreads();
    if (tid < 32) {
        s1[row0 + tid] = red1[tid][0] + red1[tid][1];
        s2[row0 + tid] = red2[tid][0] + red2[tid][1];
    }
}

// out[b][i][j] = sigmoid(s1[b*1024+i] + s2[b*1024+j] + b1)
// grid = 8192 (one block per (b,i) row), 256 thr x float4 = 1024 j's
__global__ __launch_bounds__(256) void outer_sigmoid_kernel(
    const float* __restrict__ s1, const float* __restrict__ s2,
    const float* __restrict__ b1, float* __restrict__ out)
{
    const int bi = blockIdx.x;
    const int b  = bi >> 10;
    const float base = s1[bi] + b1[0];
    const float4 t = ((const float4*)(s2 + (b << 10)))[threadIdx.x];
    float4 r;
    r.x = 1.f / (1.f + __expf(-(base + t.x)));
    r.y = 1.f / (1.f + __expf(-(base + t.y)));
    r.z = 1.f / (1.f + __expf(-(base + t.z)));
    r.w = 1.f / (1.f + __expf(-(base + t.w)));
    ((float4*)out)[((size_t)bi << 8) + threadIdx.x] = r;
}

extern "C" void kernel_launch(void* const* d_in, const int* in_sizes, int n_in,
                              void* d_out, int out_size, void* d_ws, size_t ws_size,
                              hipStream_t stream)
{
    const float* text = (const float*)d_in[0];
    // d_in[1] = mask: all-ones, unused by the reference math
    const float* W0 = (const float*)d_in[2];
    const float* b0 = (const float*)d_in[3];
    const float* W1 = (const float*)d_in[4];
    const float* b1 = (const float*)d_in[5];
    float* out = (float*)d_out;

    // workspace layout: [W0b bf16: 192 KB][s1: 32 KB][s2: 32 KB]
    unsigned short* W0b = (unsigned short*)d_ws;
    float* s1 = (float*)((char*)d_ws + (size_t)HCH * DIM * sizeof(unsigned short));
    float* s2 = s1 + M_ROWS;

    convert_w0_kernel<<<96, 256, 0, stream>>>(W0, W0b);
    gemm_s_kernel<<<256, 256, 0, stream>>>(text, W0b, b0, W1, s1, s2);
    outer_sigmoid_kernel<<<8192, 256, 0, stream>>>(s1, s2, b1, out);
}